// Round 9
// baseline (204.660 us; speedup 1.0000x reference)
//
#include <hip/hip_runtime.h>
#include <cstddef>
#include <cstdint>

#define H_    512
#define W_    512
#define NIMG  96           // 32 batch * 3 channels
#define PD_   16           // pad = KS/2
#define TY    128          // output rows per band
#define NROWS (TY + 31)    // 159 padded rows per band

// one DPP scan step: x += dpp_shifted(x); out-of-range lanes contribute 0
template <int CTRL, int RMASK>
__device__ __forceinline__ float dpp_add(float x) {
    int t = __builtin_amdgcn_update_dpp(0, __float_as_int(x), CTRL, RMASK, 0xf, true);
    return x + __int_as_float(t);
}

// wave64 inclusive prefix sum, pure VALU (6 dpp-adds, fused by GCNDPPCombine)
__device__ __forceinline__ float wave_incl_scan(float x) {
    x = dpp_add<0x111, 0xf>(x);   // row_shr:1
    x = dpp_add<0x112, 0xf>(x);   // row_shr:2
    x = dpp_add<0x114, 0xf>(x);   // row_shr:4
    x = dpp_add<0x118, 0xf>(x);   // row_shr:8
    x = dpp_add<0x142, 0xa>(x);   // row_bcast:15 -> rows 1,3
    x = dpp_add<0x143, 0xc>(x);   // row_bcast:31 -> rows 2,3
    return x;
}

__device__ __forceinline__ float bperm(int addr, float v) {
    return __int_as_float(__builtin_amdgcn_ds_bpermute(addr, __float_as_int(v)));
}

// 32-OUTPUT-COL WAVES (r6 known-good structure), plus:
//  (a) 8-deep prefetch rings: first-touch g loads are HBM (~900 cy); the old
//      4-step distance (~240-400 cy) under-covered -> vmcnt stalls. 8 steps
//      gives ~500-700 cy of cover on top of 6-waves/SIMD TLP.
//  (b) readfirstlane-forced SCALAR addressing: row indices are wave-uniform;
//      pinning them to SGPRs moves reflect+row*W math to the SALU pipe and
//      turns loads/stores into saddr+fixed-voffset form (VALU issue freed).
// Single-row body, compiler-scheduled (r8 showed manual grouping loses).
// No LDS allocation, no barriers; all cross-lane ops under full exec mask.
__global__ void __launch_bounds__(128, 4)
localnorm_kernel(const float* __restrict__ xin, float* __restrict__ out)
{
    const int tid  = threadIdx.x;
    const int lane = tid & 63;
    const int wv   = tid >> 6;

    const int c0   = blockIdx.x * 64 + wv * 32;   // wave's first output col
    const int row0 = blockIdx.y * TY;
    const int img  = blockIdx.z;

    const float* __restrict__ src = xin + (size_t)img * (H_ * W_);
    float* __restrict__ dst = out + (size_t)img * (H_ * W_) + (size_t)row0 * W_ + c0 + (lane & 31);
    const float* __restrict__ xp = src + (size_t)row0 * W_ + c0 + (lane & 31); // x base (halves dup -> 1 txn)

    // padded col (lane l = padded idx l over cols c0-16 .. c0+47) -> reflected col
    int pcm = c0 - PD_ + lane;
    const int ocm = (pcm < 0) ? -pcm : ((pcm > W_ - 1) ? 2 * (W_ - 1) - pcm : pcm);

    const bool emit = lane < 32;

    // padded row p -> reflected row pointer, forced wave-uniform (SGPR math)
    auto rowbase = [&](int p) {
        int r = row0 + p - PD_;
        r = (r < 0) ? -r : ((r > H_ - 1) ? 2 * (H_ - 1) - r : r);
        r = __builtin_amdgcn_readfirstlane(r);
        return src + (size_t)r * W_;
    };

    // 8-deep prefetch ring for the single row-load stream
    float gr[8];
#pragma unroll
    for (int p = 0; p < 8; ++p) gr[p] = rowbase(p)[ocm];

    // 32-deep f32 history of g (static idx only) + vertical rolling sums
    float hist[32];
    float vmg = 0.f, vmq = 0.f;

    // prologue: padded rows 0..30 -> accumulate only, NO scans
#pragma unroll
    for (int p = 0; p < 31; ++p) {
        float g = gr[p & 7];
        gr[p & 7] = rowbase(p + 8)[ocm];           // p+8 <= 38 < NROWS
        hist[p] = g;
        vmg += g;
        vmq = fmaf(g, g, vmq);
    }
    hist[31] = 0.f;                                // step i=0 subtracts zero

    // x-center prefetch ring, 8 deep: rows 0..7
    float xr[8];
#pragma unroll
    for (int k = 0; k < 8; ++k) {
        int xs = __builtin_amdgcn_readfirstlane(k);
        xr[k] = xp[(size_t)xs * W_];
    }

    // main: output rows 0..TY-1 in four 32-step blocks (all slots static in j)
    for (int pb = 0; pb < 4; ++pb) {
        const int ib = pb * 32;
#pragma unroll
        for (int j = 0; j < 32; ++j) {
            const int i = ib + j;                  // output row (wave-uniform)
            // new padded row p = i+31 from ring; prefetch p+8
            float g = gr[(j + 7) & 7];             // (i+31)&7 == (j+7)&7
            {   int pn = i + 39; if (pn > NROWS - 1) pn = NROWS - 1;
                gr[(j + 7) & 7] = rowbase(pn)[ocm];
            }
            // center x for this output row; prefetch row i+8
            float xv = xr[j & 7];                  // i&7 == j&7
            {   int xn = i + 8; if (xn > TY - 1) xn = TY - 1;
                xn = __builtin_amdgcn_readfirstlane(xn);
                xr[j & 7] = xp[(size_t)xn * W_];
            }

            // rolling vertical window: add row i+31, drop row i-1 (exact f32)
            float og = hist[(j + 31) & 31];
            hist[(j + 31) & 31] = g;
            vmg += g - og;
            vmq = fmaf(g, g, vmq);
            vmq = fmaf(og, -og, vmq);

            // horizontal 32-box over the 63-col window: box = S[l+31] - S[l-1]
            float sag = wave_incl_scan(vmg);
            float saq = wave_incl_scan(vmq);
            float dng = bperm(((lane + 31) & 63) << 2, sag);   // S[lane+31]
            float dnq = bperm(((lane + 31) & 63) << 2, saq);
            float sg = dng - (sag - vmg);          // 32x32 box sum of x
            float sq = dnq - (saq - vmq);          // 32x32 box sum of x^2

            // scaled epilogue: (xv - mg)/sqrt(var) == (1024 xv - sg)/sqrt(1024 sq - sg^2)
            float t  = fmaf(sq, 1024.f, 1e-12f);
            float vs = fmaf(sg, -sg, t);           // 1024^2 * var + eps
            float num = fmaf(xv, 1024.f, -sg);     // 1024 * (xv - mg)
            float r = num * __builtin_amdgcn_rsqf(vs);
            r = fminf(fmaxf(r, -6.f), 6.f);
            if (emit) {
                size_t iW = (size_t)__builtin_amdgcn_readfirstlane(i) * W_;
                dst[iW] = r;                       // lanes 0..31 carry outputs
            }
        }
    }
}

extern "C" void kernel_launch(void* const* d_in, const int* in_sizes, int n_in,
                              void* d_out, int out_size, void* d_ws, size_t ws_size,
                              hipStream_t stream) {
    (void)in_sizes; (void)n_in; (void)d_ws; (void)ws_size; (void)out_size;
    const float* x = (const float*)d_in[0];
    float* o = (float*)d_out;
    dim3 grid(W_ / 64, H_ / TY, NIMG);    // 8 x 4 x 96 = 3072 two-wave blocks, 12/CU
    localnorm_kernel<<<grid, dim3(128), 0, stream>>>(x, o);
}